// Round 5
// baseline (449.382 us; speedup 1.0000x reference)
//
#include <hip/hip_runtime.h>
#include <math.h>

// Problem constants
#define NH 8
#define DDIM 64
#define NN 2
#define QQ 128
#define PPDIM 128
#define BBD 4
#define ROWS 512           // Q*B == P*B
#define EPSN 1e-5f
#define TEMPER 30.0f

// Workspace layout (float offsets)
#define WQ_R 0u            // [H][N][512][64] rows = q*4+b
#define WQ_I 524288u
#define WK_R 1048576u      // rows = p*4+b
#define WK_I 1572864u
#define MU_  2097152u      // [4][16][64]  tensor: 0 wq_r,1 wq_i,2 wk_r,3 wk_i
#define RS_  2101248u
#define VV_  2105344u      // 4 x [H][N][512][64]  (v1,v2,v3,v4)
#define C_R_ 4202496u      // [H][N][512]
#define C_I_ 4210688u
#define ACR_ 4218880u      // [H][N][Q][B][P]   (also reused as stats scratch early)
#define ACI_ 5267456u
#define AFF_ 6316032u      // [N][Q][B][H][P]
#define PART_ ACR_         // stats partials: [256 blk][2][64]  (free until k_ac)

#define DOT4(acc, s, v)  { acc = fmaf((s).x,(v).x,acc); acc = fmaf((s).y,(v).y,acc); acc = fmaf((s).z,(v).z,acc); acc = fmaf((s).w,(v).w,acc); }
#define NDOT4(acc, s, v) { acc = fmaf(-(s).x,(v).x,acc); acc = fmaf(-(s).y,(v).y,acc); acc = fmaf(-(s).z,(v).z,acc); acc = fmaf(-(s).w,(v).w,acc); }

// ---------------------------------------------------------------------------
// K1: complex projection (pre-norm), q and k in one launch (grid.z).
// grid (16 rowtiles, 16 hn, 2 qk), block 256
// ---------------------------------------------------------------------------
__global__ __launch_bounds__(256) void k_proj(
    const float* __restrict__ qR, const float* __restrict__ qI,
    const float* __restrict__ kR, const float* __restrict__ kI,
    const float* __restrict__ WQr, const float* __restrict__ WQi,
    const float* __restrict__ WKr, const float* __restrict__ WKi,
    float* __restrict__ ws)
{
    __shared__ __align__(16) float sWT[2][64 * 64];     // transposed: [e][d]
    const int t  = threadIdx.x;
    const int rt = blockIdx.x;
    const int hn = blockIdx.y;
    const int z  = blockIdx.z;
    const int h = hn >> 1, n = hn & 1;
    const float* inR = z ? kR : qR;
    const float* inI = z ? kI : qI;
    const float* wr0 = (z ? WKr : WQr) + h * 4096;
    const float* wi0 = (z ? WKi : WQi) + h * 4096;
    float* outR = ws + (z ? WK_R : WQ_R);
    float* outI = ws + (z ? WK_I : WQ_I);
#pragma unroll
    for (int j = 0; j < 16; ++j) {
        int flat = t + 256 * j;
        int d = flat & 63, e = flat >> 6;
        sWT[0][e * 64 + d] = wr0[d * 64 + e];
        sWT[1][e * 64 + d] = wi0[d * 64 + e];
    }
    __syncthreads();
    const int row = t & 31, dq = t >> 5;     // dq 0..7, 8 outputs/thread
    const int rowg = rt * 32 + row;
    const float4* xr4 = (const float4*)(inR + (n * ROWS + rowg) * 64);
    const float4* xi4 = (const float4*)(inI + (n * ROWS + rowg) * 64);
    float ar[8], ai[8];
#pragma unroll
    for (int j = 0; j < 8; ++j) { ar[j] = 0.f; ai[j] = 0.f; }
    for (int ec = 0; ec < 16; ++ec) {
        float4 xrv = xr4[ec], xiv = xi4[ec];
        float xrs[4] = {xrv.x, xrv.y, xrv.z, xrv.w};
        float xis[4] = {xiv.x, xiv.y, xiv.z, xiv.w};
#pragma unroll
        for (int u = 0; u < 4; ++u) {
            int e = ec * 4 + u;
            const float4* wrp = (const float4*)&sWT[0][e * 64 + dq * 8];
            const float4* wip = (const float4*)&sWT[1][e * 64 + dq * 8];
            float xr = xrs[u], xi = xis[u];
#pragma unroll
            for (int j4 = 0; j4 < 2; ++j4) {
                float4 wr = wrp[j4], wi = wip[j4];
                ar[j4*4+0] = fmaf(xr, wr.x, fmaf(-xi, wi.x, ar[j4*4+0]));
                ar[j4*4+1] = fmaf(xr, wr.y, fmaf(-xi, wi.y, ar[j4*4+1]));
                ar[j4*4+2] = fmaf(xr, wr.z, fmaf(-xi, wi.z, ar[j4*4+2]));
                ar[j4*4+3] = fmaf(xr, wr.w, fmaf(-xi, wi.w, ar[j4*4+3]));
                ai[j4*4+0] = fmaf(xr, wi.x, fmaf( xi, wr.x, ai[j4*4+0]));
                ai[j4*4+1] = fmaf(xr, wi.y, fmaf( xi, wr.y, ai[j4*4+1]));
                ai[j4*4+2] = fmaf(xr, wi.z, fmaf( xi, wr.z, ai[j4*4+2]));
                ai[j4*4+3] = fmaf(xr, wi.w, fmaf( xi, wr.w, ai[j4*4+3]));
            }
        }
    }
    float* oR = outR + ((unsigned)hn * ROWS + rowg) * 64 + dq * 8;
    float* oI = outI + ((unsigned)hn * ROWS + rowg) * 64 + dq * 8;
#pragma unroll
    for (int j4 = 0; j4 < 2; ++j4) {
        ((float4*)oR)[j4] = make_float4(ar[j4*4+0], ar[j4*4+1], ar[j4*4+2], ar[j4*4+3]);
        ((float4*)oI)[j4] = make_float4(ai[j4*4+0], ai[j4*4+1], ai[j4*4+2], ai[j4*4+3]);
    }
}

// ---------------------------------------------------------------------------
// K2a: InstanceNorm partial sums.  grid 256 (= 64 groups * 4 row-chunks), block 256.
// ---------------------------------------------------------------------------
__global__ __launch_bounds__(256) void k_stats1(
    const float* __restrict__ base, float* __restrict__ part)
{
    __shared__ float sS[4][64], sQ[4][64];
    const int bid = blockIdx.x;
    const int grp = bid >> 2, cc = bid & 3;
    const int ti = grp >> 4, hn = grp & 15;
    const float* X = base + (unsigned)ti * 524288u + hn * ROWS * 64 + cc * 128 * 64;
    const int t = threadIdx.x, d = t & 63, pt = t >> 6;
    float s0 = 0.f, s1 = 0.f, q0 = 0.f, q1 = 0.f;
    for (int r = 0; r < 32; r += 2) {
        float x0 = X[(pt * 32 + r) * 64 + d];
        float x1 = X[(pt * 32 + r + 1) * 64 + d];
        s0 += x0; q0 = fmaf(x0, x0, q0);
        s1 += x1; q1 = fmaf(x1, x1, q1);
    }
    sS[pt][d] = s0 + s1; sQ[pt][d] = q0 + q1;
    __syncthreads();
    if (t < 64) {
        part[bid * 128 + t]      = sS[0][t] + sS[1][t] + sS[2][t] + sS[3][t];
        part[bid * 128 + 64 + t] = sQ[0][t] + sQ[1][t] + sQ[2][t] + sQ[3][t];
    }
}

// K2b: finalize stats.  grid 64 (= groups), block 64.
__global__ __launch_bounds__(64) void k_stats2(
    const float* __restrict__ part, float* __restrict__ mu, float* __restrict__ rs)
{
    const int grp = blockIdx.x, d = threadIdx.x;
    float s = 0.f, q = 0.f;
#pragma unroll
    for (int cc = 0; cc < 4; ++cc) {
        s += part[(grp * 4 + cc) * 128 + d];
        q += part[(grp * 4 + cc) * 128 + 64 + d];
    }
    float m = s * (1.f / 512.f);
    float var = q * (1.f / 512.f) - m * m;
    mu[grp * 64 + d] = m;
    rs[grp * 64 + d] = rsqrtf(var + EPSN);
}

// ---------------------------------------------------------------------------
// K3: v-vectors v1..v4 = {WKRr,WKRi}^T {wr_qr, wr_qi}, and bias dot terms.
// grid (32 = rt(16) + 16*eh(2), 16 hn), block 256
// ---------------------------------------------------------------------------
__global__ __launch_bounds__(256) void k_vvec(
    const float* __restrict__ wqr, const float* __restrict__ wqi,
    const float* __restrict__ mu,  const float* __restrict__ rs,
    const float* __restrict__ Ar,  const float* __restrict__ Ai,
    const float* __restrict__ Abr, const float* __restrict__ Abi,
    const float* __restrict__ gr,  const float* __restrict__ btr,
    const float* __restrict__ gi,  const float* __restrict__ bti,
    float* __restrict__ Vout, float* __restrict__ cR, float* __restrict__ cI)
{
    __shared__ __align__(16) float sW[2][2048];   // [d 64][e'_half 32]
    __shared__ float sX[2][2048];                 // swizzled [d 64][row 32]
    const int t = threadIdx.x;
    const int bx = blockIdx.x, rt = bx & 15, eh = bx >> 4;
    const int hn = blockIdx.y, h = hn >> 1;
    const float* a0 = Ar + h * 4096;
    const float* a1 = Ai + h * 4096;
#pragma unroll
    for (int j = 0; j < 8; ++j) {
        int flat = t + 256 * j;
        int c = flat & 31, r = flat >> 5;
        sW[0][r * 32 + c] = a0[r * 64 + eh * 32 + c];
        sW[1][r * 32 + c] = a1[r * 64 + eh * 32 + c];
    }
    const float* mu0 = mu + hn * 64;        const float* rs0 = rs + hn * 64;
    const float* mu1 = mu + (16 + hn) * 64; const float* rs1 = rs + (16 + hn) * 64;
    {
        const int d = t & 63;
        const float m0 = mu0[d], r0 = rs0[d], g0 = gr[h * 64 + d], b0 = btr[h * 64 + d];
        const float m1 = mu1[d], r1 = rs1[d], g1 = gi[h * 64 + d], b1 = bti[h * 64 + d];
#pragma unroll
        for (int j = 0; j < 8; ++j) {
            int row = (t >> 6) + 4 * j;  // 0..31
            int gidx = (hn * ROWS + rt * 32 + row) * 64 + d;
            float xr = wqr[gidx], xi = wqi[gidx];
            sX[0][d * 32 + ((row + d) & 31)] = (xr - m0) * r0 * g0 + b0;
            sX[1][d * 32 + ((row + d) & 31)] = (xi - m1) * r1 * g1 + b1;
        }
    }
    __syncthreads();
    const int row = t & 31, eq = t >> 5;   // eq 0..7 -> 4 outputs each
    float v[4][4];
#pragma unroll
    for (int k = 0; k < 4; ++k)
#pragma unroll
        for (int j = 0; j < 4; ++j) v[k][j] = 0.f;
    for (int d = 0; d < 64; ++d) {
        float xr = sX[0][d * 32 + ((row + d) & 31)];
        float xi = sX[1][d * 32 + ((row + d) & 31)];
        float4 wr = *(const float4*)&sW[0][d * 32 + eq * 4];
        float4 wi = *(const float4*)&sW[1][d * 32 + eq * 4];
        v[0][0] = fmaf(xr, wr.x, v[0][0]); v[0][1] = fmaf(xr, wr.y, v[0][1]);
        v[0][2] = fmaf(xr, wr.z, v[0][2]); v[0][3] = fmaf(xr, wr.w, v[0][3]);
        v[1][0] = fmaf(xr, wi.x, v[1][0]); v[1][1] = fmaf(xr, wi.y, v[1][1]);
        v[1][2] = fmaf(xr, wi.z, v[1][2]); v[1][3] = fmaf(xr, wi.w, v[1][3]);
        v[2][0] = fmaf(xi, wr.x, v[2][0]); v[2][1] = fmaf(xi, wr.y, v[2][1]);
        v[2][2] = fmaf(xi, wr.z, v[2][2]); v[2][3] = fmaf(xi, wr.w, v[2][3]);
        v[3][0] = fmaf(xi, wi.x, v[3][0]); v[3][1] = fmaf(xi, wi.y, v[3][1]);
        v[3][2] = fmaf(xi, wi.z, v[3][2]); v[3][3] = fmaf(xi, wi.w, v[3][3]);
    }
    const int rowg = rt * 32 + row;
#pragma unroll
    for (int k = 0; k < 4; ++k) {
        float* o = Vout + (unsigned)k * 524288u + (hn * ROWS + rowg) * 64 + eh * 32 + eq * 4;
        *(float4*)o = make_float4(v[k][0], v[k][1], v[k][2], v[k][3]);
    }
    if (eh == 0 && t < 32) {
        const int rw = t;
        float cr = 0.f, ci = 0.f;
        for (int d = 0; d < 64; ++d) {
            float br = Abr[h * 64 + d], bi = Abi[h * 64 + d];
            float bm = br - bi, bp = br + bi;
            float xr = sX[0][d * 32 + ((rw + d) & 31)];
            float xi = sX[1][d * 32 + ((rw + d) & 31)];
            cr = fmaf(bm, xr, fmaf(-bp, xi, cr));
            ci = fmaf(bm, xi, fmaf( bp, xr, ci));
        }
        cR[hn * ROWS + rt * 32 + rw] = cr;
        cI[hn * ROWS + rt * 32 + rw] = ci;
    }
}

// ---------------------------------------------------------------------------
// K4: AC scores. grid (16 = qt(8) + 8*ph(2), 16 hn, 4 b), block 256
// ---------------------------------------------------------------------------
__global__ __launch_bounds__(256) void k_ac(
    const float* __restrict__ wqr, const float* __restrict__ wqi,
    const float* __restrict__ wkr, const float* __restrict__ wki,
    const float* __restrict__ mu,  const float* __restrict__ rs,
    const float* __restrict__ gwr, const float* __restrict__ btwr,
    const float* __restrict__ gwi, const float* __restrict__ btwi,
    float* __restrict__ ACr, float* __restrict__ ACi)
{
    __shared__ float sK[2][64][65];
    __shared__ float sQT[2][64][20];   // [d][16 q + pad]
    const int t = threadIdx.x;
    const int bx = blockIdx.x, qt = bx & 7, ph = bx >> 3;
    const int hn = blockIdx.y, h = hn >> 1;
    const int b = blockIdx.z;
    const float* mu2 = mu + (32 + hn) * 64; const float* rs2 = rs + (32 + hn) * 64;
    const float* mu3 = mu + (48 + hn) * 64; const float* rs3 = rs + (48 + hn) * 64;
#pragma unroll
    for (int j = 0; j < 4; ++j) {
        int flat4 = t + 256 * j;
        int word = flat4 * 4;
        int pp = word >> 6, ee = word & 63;
        int gidx = (hn * ROWS + (ph * 64 + pp) * 4 + b) * 64 + ee;
        float4 kr = *(const float4*)&wkr[gidx];
        float4 ki = *(const float4*)&wki[gidx];
        float4 m2 = *(const float4*)&mu2[ee]; float4 r2 = *(const float4*)&rs2[ee];
        float4 m3 = *(const float4*)&mu3[ee]; float4 r3 = *(const float4*)&rs3[ee];
        sK[0][pp][ee+0] = (kr.x - m2.x) * r2.x; sK[0][pp][ee+1] = (kr.y - m2.y) * r2.y;
        sK[0][pp][ee+2] = (kr.z - m2.z) * r2.z; sK[0][pp][ee+3] = (kr.w - m2.w) * r2.w;
        sK[1][pp][ee+0] = (ki.x - m3.x) * r3.x; sK[1][pp][ee+1] = (ki.y - m3.y) * r3.y;
        sK[1][pp][ee+2] = (ki.z - m3.z) * r3.z; sK[1][pp][ee+3] = (ki.w - m3.w) * r3.w;
    }
    const float* mu0 = mu + hn * 64;        const float* rs0 = rs + hn * 64;
    const float* mu1 = mu + (16 + hn) * 64; const float* rs1 = rs + (16 + hn) * 64;
    {
        int word = t * 4;
        int qq = word >> 6, dd = word & 63;          // qq 0..15
        int gidx = (hn * ROWS + (qt * 16 + qq) * 4 + b) * 64 + dd;
        float4 xr = *(const float4*)&wqr[gidx];
        float4 xi = *(const float4*)&wqi[gidx];
        float4 m0 = *(const float4*)&mu0[dd]; float4 r0 = *(const float4*)&rs0[dd];
        float4 m1 = *(const float4*)&mu1[dd]; float4 r1 = *(const float4*)&rs1[dd];
        float4 g0 = *(const float4*)&gwr[h * 64 + dd]; float4 b0 = *(const float4*)&btwr[h * 64 + dd];
        float4 g1 = *(const float4*)&gwi[h * 64 + dd]; float4 b1 = *(const float4*)&btwi[h * 64 + dd];
        sQT[0][dd+0][qq] = fmaf((xr.x - m0.x) * r0.x, g0.x, b0.x);
        sQT[0][dd+1][qq] = fmaf((xr.y - m0.y) * r0.y, g0.y, b0.y);
        sQT[0][dd+2][qq] = fmaf((xr.z - m0.z) * r0.z, g0.z, b0.z);
        sQT[0][dd+3][qq] = fmaf((xr.w - m0.w) * r0.w, g0.w, b0.w);
        sQT[1][dd+0][qq] = fmaf((xi.x - m1.x) * r1.x, g1.x, b1.x);
        sQT[1][dd+1][qq] = fmaf((xi.y - m1.y) * r1.y, g1.y, b1.y);
        sQT[1][dd+2][qq] = fmaf((xi.z - m1.z) * r1.z, g1.z, b1.z);
        sQT[1][dd+3][qq] = fmaf((xi.w - m1.w) * r1.w, g1.w, b1.w);
    }
    __syncthreads();
    const int p = t & 63, qs = t >> 6;
    float acr[4], aci[4];
#pragma unroll
    for (int j = 0; j < 4; ++j) { acr[j] = 0.f; aci[j] = 0.f; }
    for (int e = 0; e < 64; ++e) {
        float kr = sK[0][p][e], ki = sK[1][p][e];
        float4 qr = *(const float4*)&sQT[0][e][qs * 4];
        float4 qi = *(const float4*)&sQT[1][e][qs * 4];
        acr[0] = fmaf(kr, qr.x, fmaf(-ki, qi.x, acr[0]));
        acr[1] = fmaf(kr, qr.y, fmaf(-ki, qi.y, acr[1]));
        acr[2] = fmaf(kr, qr.z, fmaf(-ki, qi.z, acr[2]));
        acr[3] = fmaf(kr, qr.w, fmaf(-ki, qi.w, acr[3]));
        aci[0] = fmaf(kr, qi.x, fmaf( ki, qr.x, aci[0]));
        aci[1] = fmaf(kr, qi.y, fmaf( ki, qr.y, aci[1]));
        aci[2] = fmaf(kr, qi.z, fmaf( ki, qr.z, aci[2]));
        aci[3] = fmaf(kr, qi.w, fmaf( ki, qr.w, aci[3]));
    }
#pragma unroll
    for (int j = 0; j < 4; ++j) {
        int q = qt * 16 + qs * 4 + j;
        int oidx = ((hn * 128 + q) * 4 + b) * 128 + ph * 64 + p;
        ACr[oidx] = acr[j];
        ACi[oidx] = aci[j];
    }
}

// ---------------------------------------------------------------------------
// K5 v5: fused BD + AC + affinity + softmax.  wave = b, lane = (eo 16, pl 4).
// Vv staged in LDS once per block (kills the per-h global-load latency chains).
// LDS union: Vv region reused as epilogue transpose scratch.
// grid (256 nq, 8 pq)  -> pq-siblings share an XCD (Vv L2 locality).
// ---------------------------------------------------------------------------
__global__ __launch_bounds__(256, 3) void k_bd(
    const float* __restrict__ ER, const float* __restrict__ EI,
    const float* __restrict__ Vv, const float* __restrict__ cR, const float* __restrict__ cI,
    const float* __restrict__ ACr, const float* __restrict__ ACi,
    float* __restrict__ AFF)
{
    __shared__ __align__(16) float uS[8704]; // main: sVv [b][h][k][e] (8192); epi: 4x2176 scratch
    __shared__ float sL[128 * 5];            // logits [c][b]
    const int t = threadIdx.x;
    const int w = t >> 6;            // wave = b
    const int l = t & 63;
    const int eo = l & 15, pl = l >> 4;
    const int nq = blockIdx.x;
    const int pq = blockIdx.y;
    const int n = nq >> 7, q = nq & 127;
    const int P0 = pq * 16;

    // ---- stage Vv: 8 KB per b, 32 KB total, coalesced ----
#pragma unroll
    for (int it = 0; it < 8; ++it) {
        int flat = t + 256 * it;                 // float4 units
        int e4 = flat & 15, k = (flat >> 4) & 3, h = (flat >> 6) & 7, bb = flat >> 9;
        float4 x = *(const float4*)&Vv[(unsigned)k * 524288u
                                       + ((h * 2 + n) * ROWS + q * 4 + bb) * 64u + e4 * 4];
        *(float4*)&uS[bb * 2048 + (h * 4 + k) * 64 + e4 * 4] = x;
    }
    __syncthreads();

    float accr[8][4], acci[8][4];
#pragma unroll
    for (int h = 0; h < 8; ++h)
#pragma unroll
        for (int j = 0; j < 4; ++j) { accr[h][j] = 0.f; acci[h][j] = 0.f; }

#pragma unroll
    for (int jc = 0; jc < 2; ++jc) {
        float4 A[2], Bv[2], C4[2], D4[2];
#pragma unroll
        for (int jj = 0; jj < 2; ++jj) {
            int j = jc * 2 + jj;
            int p = P0 + pl * 4 + j;
            int qpo = (((n * 128 + q) * 128 + p) * 4 + w) * 64 + eo * 4;
            int pqo = (((n * 128 + p) * 128 + q) * 4 + w) * 64 + eo * 4;
            A[jj]  = *(const float4*)(ER + qpo);
            Bv[jj] = *(const float4*)(EI + qpo);
            C4[jj] = *(const float4*)(ER + pqo);
            D4[jj] = *(const float4*)(EI + pqo);
        }
#pragma unroll
        for (int h = 0; h < 8; ++h) {
            const float* vb = &uS[w * 2048 + h * 256 + eo * 4];
            float4 v1 = *(const float4*)(vb);
            float4 v2 = *(const float4*)(vb + 64);
            float4 v3 = *(const float4*)(vb + 128);
            float4 v4 = *(const float4*)(vb + 192);
#pragma unroll
            for (int jj = 0; jj < 2; ++jj) {
                int j = jc * 2 + jj;
                DOT4 (accr[h][j], A[jj],  v1);
                NDOT4(accr[h][j], Bv[jj], v2);
                NDOT4(accr[h][j], C4[jj], v4);
                NDOT4(accr[h][j], D4[jj], v3);
                DOT4 (acci[h][j], A[jj],  v3);
                NDOT4(acci[h][j], Bv[jj], v4);
                DOT4 (acci[h][j], C4[jj], v2);
                DOT4 (acci[h][j], D4[jj], v1);
            }
        }
    }

    // Output assignments: lane l handles c1 = l (h 0..3) and c2 = l+64 (h 4..7)
    const int c1 = l, c2 = l + 64;
    const int h1 = c1 >> 4, h2 = h1 + 4;
    const int pc = c1 & 15;
    const int jr = pc >> 2, plr = pc & 3;
    const int poff = plr * 4 + jr;
    // prefetch AC + c (L2-hot, latency overlaps LDS reduction)
    float ac_r1 = ACr[(((h1 * 2 + n) * 128 + q) * 4 + w) * 128 + P0 + poff];
    float ac_i1 = ACi[(((h1 * 2 + n) * 128 + q) * 4 + w) * 128 + P0 + poff];
    float ac_r2 = ACr[(((h2 * 2 + n) * 128 + q) * 4 + w) * 128 + P0 + poff];
    float ac_i2 = ACi[(((h2 * 2 + n) * 128 + q) * 4 + w) * 128 + P0 + poff];
    float cr1 = cR[(h1 * 2 + n) * ROWS + q * 4 + w];
    float ci1 = cI[(h1 * 2 + n) * ROWS + q * 4 + w];
    float cr2 = cR[(h2 * 2 + n) * ROWS + q * 4 + w];
    float ci2 = cI[(h2 * 2 + n) * ROWS + q * 4 + w];

    __syncthreads();                  // Vv region dead -> safe to reuse as scratch
    float* wb = uS + w * 2176;
    // ---- r pass ----
#pragma unroll
    for (int h = 0; h < 8; ++h)
#pragma unroll
        for (int j = 0; j < 4; ++j)
            wb[(h * 16 + j * 4 + pl) * 17 + eo] = accr[h][j];
    __syncthreads();
    float bdr1 = 0.f, bdr2 = 0.f;
#pragma unroll
    for (int i = 0; i < 16; ++i) {
        bdr1 += wb[c1 * 17 + i];
        bdr2 += wb[c2 * 17 + i];
    }
    __syncthreads();
    // ---- i pass ----
#pragma unroll
    for (int h = 0; h < 8; ++h)
#pragma unroll
        for (int j = 0; j < 4; ++j)
            wb[(h * 16 + j * 4 + pl) * 17 + eo] = acci[h][j];
    __syncthreads();
    float bdi1 = 0.f, bdi2 = 0.f;
#pragma unroll
    for (int i = 0; i < 16; ++i) {
        bdi1 += wb[c1 * 17 + i];
        bdi2 += wb[c2 * 17 + i];
    }

    bdr1 += cr1; bdi1 += ci1;
    bdr2 += cr2; bdi2 += ci2;
    float aff1 = sqrtf(fmaf(ac_r1, ac_r1, ac_i1 * ac_i1)) + sqrtf(fmaf(bdr1, bdr1, bdi1 * bdi1));
    float aff2 = sqrtf(fmaf(ac_r2, ac_r2, ac_i2 * ac_i2)) + sqrtf(fmaf(bdr2, bdr2, bdi2 * bdi2));
    float lg1 = aff1 * TEMPER, lg2 = aff2 * TEMPER;
    sL[c1 * 5 + w] = lg1;
    sL[c2 * 5 + w] = lg2;
    __syncthreads();
    {
        float l0 = sL[c1 * 5 + 0], l1x = sL[c1 * 5 + 1], l2x = sL[c1 * 5 + 2], l3x = sL[c1 * 5 + 3];
        float m = fmaxf(fmaxf(l0, l1x), fmaxf(l2x, l3x));
        float s = __expf(l0 - m) + __expf(l1x - m) + __expf(l2x - m) + __expf(l3x - m);
        AFF[(unsigned)((nq * 4 + w) * 8 + h1) * 128 + P0 + poff] = __expf(lg1 - m) / s;
    }
    {
        float l0 = sL[c2 * 5 + 0], l1x = sL[c2 * 5 + 1], l2x = sL[c2 * 5 + 2], l3x = sL[c2 * 5 + 3];
        float m = fmaxf(fmaxf(l0, l1x), fmaxf(l2x, l3x));
        float s = __expf(l0 - m) + __expf(l1x - m) + __expf(l2x - m) + __expf(l3x - m);
        AFF[(unsigned)((nq * 4 + w) * 8 + h2) * 128 + P0 + poff] = __expf(lg2 - m) / s;
    }
}

// ---------------------------------------------------------------------------
// K6 v2: PV contraction. AFF layout [n][q][b][h][p].
// grid 1024, block 256
// ---------------------------------------------------------------------------
__global__ __launch_bounds__(256) void k_pv(
    const float* __restrict__ AFF,
    const float* __restrict__ Vr, const float* __restrict__ Vi,
    float* __restrict__ out)
{
    __shared__ float sA[8 * 132];
    __shared__ float sRed[4 * 1092];
    const int t = threadIdx.x;
    const int nqb = blockIdx.x;
    const int b = nqb & 3, q = (nqb >> 2) & 127, n = nqb >> 9;
#pragma unroll
    for (int j = 0; j < 4; ++j) {
        int idx = t + 256 * j;
        sA[(idx >> 7) * 132 + (idx & 127)] = AFF[(unsigned)nqb * 1024u + idx];
    }
    __syncthreads();
    const int d = t & 63, pp = t >> 6;
    const float* vr = Vr + (n * 512 + b) * 64 + d;
    const float* vi = Vi + (n * 512 + b) * 64 + d;
    float oR[8], oI[8];
#pragma unroll
    for (int h = 0; h < 8; ++h) { oR[h] = 0.f; oI[h] = 0.f; }
    for (int pz = 0; pz < 32; ++pz) {
        int p = pp * 32 + pz;
        float xr = vr[p * 256];
        float xi = vi[p * 256];
#pragma unroll
        for (int h = 0; h < 8; ++h) {
            float a = sA[h * 132 + p];
            oR[h] = fmaf(a, xr, oR[h]);
            oI[h] = fmaf(a, xi, oI[h]);
        }
    }
    float* wb = sRed + pp * 1092;
#pragma unroll
    for (int s = 0; s < 16; ++s) {
        int h = s >> 1;
        wb[d * 17 + s] = (s & 1) ? oI[h] : oR[h];
    }
    __syncthreads();
    const int d2 = t & 63, g = t >> 6;
#pragma unroll
    for (int k = 0; k < 4; ++k) {
        int s = g * 4 + k;
        float v = sRed[0 * 1092 + d2 * 17 + s] + sRed[1 * 1092 + d2 * 17 + s]
                + sRed[2 * 1092 + d2 * 17 + s] + sRed[3 * 1092 + d2 * 17 + s];
        int h = s >> 1, ri = s & 1;
        out[(unsigned)ri * 524288u + ((n * 128 + q) * 4 + b) * 512u + h * 64 + d2] = v;
    }
}

// ---------------------------------------------------------------------------
extern "C" void kernel_launch(void* const* d_in, const int* in_sizes, int n_in,
                              void* d_out, int out_size, void* d_ws, size_t ws_size,
                              hipStream_t stream) {
    (void)in_sizes; (void)n_in; (void)out_size; (void)ws_size;
    const float* q_r  = (const float*)d_in[0];
    const float* q_i  = (const float*)d_in[1];
    const float* k_r  = (const float*)d_in[2];
    const float* k_i  = (const float*)d_in[3];
    const float* v_r  = (const float*)d_in[4];
    const float* v_i  = (const float*)d_in[5];
    const float* e_r  = (const float*)d_in[6];
    const float* e_i  = (const float*)d_in[7];
    const float* WKr_w  = (const float*)d_in[8];
    const float* WKi_w  = (const float*)d_in[10];
    const float* WKRr_w = (const float*)d_in[12];
    const float* WKRr_b = (const float*)d_in[13];
    const float* WKRi_w = (const float*)d_in[14];
    const float* WKRi_b = (const float*)d_in[15];
    const float* WQr_w  = (const float*)d_in[16];
    const float* WQi_w  = (const float*)d_in[18];
    const float* ww_r_g  = (const float*)d_in[20];
    const float* ww_r_bt = (const float*)d_in[21];
    const float* ww_i_g  = (const float*)d_in[22];
    const float* ww_i_bt = (const float*)d_in[23];
    const float* wr_r_g  = (const float*)d_in[24];
    const float* wr_r_bt = (const float*)d_in[25];
    const float* wr_i_g  = (const float*)d_in[26];
    const float* wr_i_bt = (const float*)d_in[27];
    float* ws  = (float*)d_ws;
    float* out = (float*)d_out;

    k_proj<<<dim3(16, 16, 2), 256, 0, stream>>>(q_r, q_i, k_r, k_i,
                                                WQr_w, WQi_w, WKr_w, WKi_w, ws);
    k_stats1<<<256, 256, 0, stream>>>(ws + WQ_R, ws + PART_);
    k_stats2<<<64, 64, 0, stream>>>(ws + PART_, ws + MU_, ws + RS_);
    k_vvec<<<dim3(32, 16), 256, 0, stream>>>(ws + WQ_R, ws + WQ_I, ws + MU_, ws + RS_,
                                             WKRr_w, WKRi_w, WKRr_b, WKRi_b,
                                             wr_r_g, wr_r_bt, wr_i_g, wr_i_bt,
                                             ws + VV_, ws + C_R_, ws + C_I_);
    k_ac<<<dim3(16, 16, 4), 256, 0, stream>>>(ws + WQ_R, ws + WQ_I, ws + WK_R, ws + WK_I,
                                              ws + MU_, ws + RS_,
                                              ww_r_g, ww_r_bt, ww_i_g, ww_i_bt,
                                              ws + ACR_, ws + ACI_);
    k_bd<<<dim3(256, 8), 256, 0, stream>>>(e_r, e_i, ws + VV_, ws + C_R_, ws + C_I_,
                                           ws + ACR_, ws + ACI_, ws + AFF_);
    k_pv<<<1024, 256, 0, stream>>>(ws + AFF_, v_r, v_i, out);
}

// Round 6
// 250.063 us; speedup vs baseline: 1.7971x; 1.7971x over previous
//
#include <hip/hip_runtime.h>
#include <math.h>

// Problem constants
#define NH 8
#define DDIM 64
#define NN 2
#define QQ 128
#define PPDIM 128
#define BBD 4
#define ROWS 512           // Q*B == P*B
#define EPSN 1e-5f
#define TEMPER 30.0f

// Workspace layout (float offsets)
#define WQ_R 0u            // [H][N][512][64] rows = q*4+b
#define WQ_I 524288u
#define WK_R 1048576u      // rows = p*4+b
#define WK_I 1572864u
#define MU_  2097152u      // [4][16][64]  tensor: 0 wq_r,1 wq_i,2 wk_r,3 wk_i
#define RS_  2101248u
#define VV_  2105344u      // 4 x [H][N][512][64]  (v1,v2,v3,v4)
#define C_R_ 4202496u      // [H][N][512]
#define C_I_ 4210688u
#define ACR_ 4218880u      // [H][N][Q][B][P]   (also reused as stats scratch early)
#define ACI_ 5267456u
#define AFF_ 6316032u      // [N][Q][B][H][P]
#define PART_ ACR_         // stats partials: [256 blk][2][64]  (free until k_ac)

#define DOT4(acc, s, v)  { acc = fmaf((s).x,(v).x,acc); acc = fmaf((s).y,(v).y,acc); acc = fmaf((s).z,(v).z,acc); acc = fmaf((s).w,(v).w,acc); }
#define NDOT4(acc, s, v) { acc = fmaf(-(s).x,(v).x,acc); acc = fmaf(-(s).y,(v).y,acc); acc = fmaf(-(s).z,(v).z,acc); acc = fmaf(-(s).w,(v).w,acc); }

// ---------------------------------------------------------------------------
// K1: complex projection (pre-norm), q and k in one launch (grid.z).
// grid (16 rowtiles, 16 hn, 2 qk), block 256
// ---------------------------------------------------------------------------
__global__ __launch_bounds__(256) void k_proj(
    const float* __restrict__ qR, const float* __restrict__ qI,
    const float* __restrict__ kR, const float* __restrict__ kI,
    const float* __restrict__ WQr, const float* __restrict__ WQi,
    const float* __restrict__ WKr, const float* __restrict__ WKi,
    float* __restrict__ ws)
{
    __shared__ __align__(16) float sWT[2][64 * 64];     // transposed: [e][d]
    const int t  = threadIdx.x;
    const int rt = blockIdx.x;
    const int hn = blockIdx.y;
    const int z  = blockIdx.z;
    const int h = hn >> 1, n = hn & 1;
    const float* inR = z ? kR : qR;
    const float* inI = z ? kI : qI;
    const float* wr0 = (z ? WKr : WQr) + h * 4096;
    const float* wi0 = (z ? WKi : WQi) + h * 4096;
    float* outR = ws + (z ? WK_R : WQ_R);
    float* outI = ws + (z ? WK_I : WQ_I);
#pragma unroll
    for (int j = 0; j < 16; ++j) {
        int flat = t + 256 * j;
        int d = flat & 63, e = flat >> 6;
        sWT[0][e * 64 + d] = wr0[d * 64 + e];
        sWT[1][e * 64 + d] = wi0[d * 64 + e];
    }
    __syncthreads();
    const int row = t & 31, dq = t >> 5;     // dq 0..7, 8 outputs/thread
    const int rowg = rt * 32 + row;
    const float4* xr4 = (const float4*)(inR + (n * ROWS + rowg) * 64);
    const float4* xi4 = (const float4*)(inI + (n * ROWS + rowg) * 64);
    float ar[8], ai[8];
#pragma unroll
    for (int j = 0; j < 8; ++j) { ar[j] = 0.f; ai[j] = 0.f; }
    for (int ec = 0; ec < 16; ++ec) {
        float4 xrv = xr4[ec], xiv = xi4[ec];
        float xrs[4] = {xrv.x, xrv.y, xrv.z, xrv.w};
        float xis[4] = {xiv.x, xiv.y, xiv.z, xiv.w};
#pragma unroll
        for (int u = 0; u < 4; ++u) {
            int e = ec * 4 + u;
            const float4* wrp = (const float4*)&sWT[0][e * 64 + dq * 8];
            const float4* wip = (const float4*)&sWT[1][e * 64 + dq * 8];
            float xr = xrs[u], xi = xis[u];
#pragma unroll
            for (int j4 = 0; j4 < 2; ++j4) {
                float4 wr = wrp[j4], wi = wip[j4];
                ar[j4*4+0] = fmaf(xr, wr.x, fmaf(-xi, wi.x, ar[j4*4+0]));
                ar[j4*4+1] = fmaf(xr, wr.y, fmaf(-xi, wi.y, ar[j4*4+1]));
                ar[j4*4+2] = fmaf(xr, wr.z, fmaf(-xi, wi.z, ar[j4*4+2]));
                ar[j4*4+3] = fmaf(xr, wr.w, fmaf(-xi, wi.w, ar[j4*4+3]));
                ai[j4*4+0] = fmaf(xr, wi.x, fmaf( xi, wr.x, ai[j4*4+0]));
                ai[j4*4+1] = fmaf(xr, wi.y, fmaf( xi, wr.y, ai[j4*4+1]));
                ai[j4*4+2] = fmaf(xr, wi.z, fmaf( xi, wr.z, ai[j4*4+2]));
                ai[j4*4+3] = fmaf(xr, wi.w, fmaf( xi, wr.w, ai[j4*4+3]));
            }
        }
    }
    float* oR = outR + ((unsigned)hn * ROWS + rowg) * 64 + dq * 8;
    float* oI = outI + ((unsigned)hn * ROWS + rowg) * 64 + dq * 8;
#pragma unroll
    for (int j4 = 0; j4 < 2; ++j4) {
        ((float4*)oR)[j4] = make_float4(ar[j4*4+0], ar[j4*4+1], ar[j4*4+2], ar[j4*4+3]);
        ((float4*)oI)[j4] = make_float4(ai[j4*4+0], ai[j4*4+1], ai[j4*4+2], ai[j4*4+3]);
    }
}

// ---------------------------------------------------------------------------
// K2a: InstanceNorm partial sums.  grid 256 (= 64 groups * 4 row-chunks), block 256.
// ---------------------------------------------------------------------------
__global__ __launch_bounds__(256) void k_stats1(
    const float* __restrict__ base, float* __restrict__ part)
{
    __shared__ float sS[4][64], sQ[4][64];
    const int bid = blockIdx.x;
    const int grp = bid >> 2, cc = bid & 3;
    const int ti = grp >> 4, hn = grp & 15;
    const float* X = base + (unsigned)ti * 524288u + hn * ROWS * 64 + cc * 128 * 64;
    const int t = threadIdx.x, d = t & 63, pt = t >> 6;
    float s0 = 0.f, s1 = 0.f, q0 = 0.f, q1 = 0.f;
    for (int r = 0; r < 32; r += 2) {
        float x0 = X[(pt * 32 + r) * 64 + d];
        float x1 = X[(pt * 32 + r + 1) * 64 + d];
        s0 += x0; q0 = fmaf(x0, x0, q0);
        s1 += x1; q1 = fmaf(x1, x1, q1);
    }
    sS[pt][d] = s0 + s1; sQ[pt][d] = q0 + q1;
    __syncthreads();
    if (t < 64) {
        part[bid * 128 + t]      = sS[0][t] + sS[1][t] + sS[2][t] + sS[3][t];
        part[bid * 128 + 64 + t] = sQ[0][t] + sQ[1][t] + sQ[2][t] + sQ[3][t];
    }
}

// K2b: finalize stats.  grid 64 (= groups), block 64.
__global__ __launch_bounds__(64) void k_stats2(
    const float* __restrict__ part, float* __restrict__ mu, float* __restrict__ rs)
{
    const int grp = blockIdx.x, d = threadIdx.x;
    float s = 0.f, q = 0.f;
#pragma unroll
    for (int cc = 0; cc < 4; ++cc) {
        s += part[(grp * 4 + cc) * 128 + d];
        q += part[(grp * 4 + cc) * 128 + 64 + d];
    }
    float m = s * (1.f / 512.f);
    float var = q * (1.f / 512.f) - m * m;
    mu[grp * 64 + d] = m;
    rs[grp * 64 + d] = rsqrtf(var + EPSN);
}

// ---------------------------------------------------------------------------
// K3: v-vectors v1..v4 = {WKRr,WKRi}^T {wr_qr, wr_qi}, and bias dot terms.
// grid (32 = rt(16) + 16*eh(2), 16 hn), block 256
// ---------------------------------------------------------------------------
__global__ __launch_bounds__(256) void k_vvec(
    const float* __restrict__ wqr, const float* __restrict__ wqi,
    const float* __restrict__ mu,  const float* __restrict__ rs,
    const float* __restrict__ Ar,  const float* __restrict__ Ai,
    const float* __restrict__ Abr, const float* __restrict__ Abi,
    const float* __restrict__ gr,  const float* __restrict__ btr,
    const float* __restrict__ gi,  const float* __restrict__ bti,
    float* __restrict__ Vout, float* __restrict__ cR, float* __restrict__ cI)
{
    __shared__ __align__(16) float sW[2][2048];   // [d 64][e'_half 32]
    __shared__ float sX[2][2048];                 // swizzled [d 64][row 32]
    const int t = threadIdx.x;
    const int bx = blockIdx.x, rt = bx & 15, eh = bx >> 4;
    const int hn = blockIdx.y, h = hn >> 1;
    const float* a0 = Ar + h * 4096;
    const float* a1 = Ai + h * 4096;
#pragma unroll
    for (int j = 0; j < 8; ++j) {
        int flat = t + 256 * j;
        int c = flat & 31, r = flat >> 5;
        sW[0][r * 32 + c] = a0[r * 64 + eh * 32 + c];
        sW[1][r * 32 + c] = a1[r * 64 + eh * 32 + c];
    }
    const float* mu0 = mu + hn * 64;        const float* rs0 = rs + hn * 64;
    const float* mu1 = mu + (16 + hn) * 64; const float* rs1 = rs + (16 + hn) * 64;
    {
        const int d = t & 63;
        const float m0 = mu0[d], r0 = rs0[d], g0 = gr[h * 64 + d], b0 = btr[h * 64 + d];
        const float m1 = mu1[d], r1 = rs1[d], g1 = gi[h * 64 + d], b1 = bti[h * 64 + d];
#pragma unroll
        for (int j = 0; j < 8; ++j) {
            int row = (t >> 6) + 4 * j;  // 0..31
            int gidx = (hn * ROWS + rt * 32 + row) * 64 + d;
            float xr = wqr[gidx], xi = wqi[gidx];
            sX[0][d * 32 + ((row + d) & 31)] = (xr - m0) * r0 * g0 + b0;
            sX[1][d * 32 + ((row + d) & 31)] = (xi - m1) * r1 * g1 + b1;
        }
    }
    __syncthreads();
    const int row = t & 31, eq = t >> 5;   // eq 0..7 -> 4 outputs each
    float v[4][4];
#pragma unroll
    for (int k = 0; k < 4; ++k)
#pragma unroll
        for (int j = 0; j < 4; ++j) v[k][j] = 0.f;
    for (int d = 0; d < 64; ++d) {
        float xr = sX[0][d * 32 + ((row + d) & 31)];
        float xi = sX[1][d * 32 + ((row + d) & 31)];
        float4 wr = *(const float4*)&sW[0][d * 32 + eq * 4];
        float4 wi = *(const float4*)&sW[1][d * 32 + eq * 4];
        v[0][0] = fmaf(xr, wr.x, v[0][0]); v[0][1] = fmaf(xr, wr.y, v[0][1]);
        v[0][2] = fmaf(xr, wr.z, v[0][2]); v[0][3] = fmaf(xr, wr.w, v[0][3]);
        v[1][0] = fmaf(xr, wi.x, v[1][0]); v[1][1] = fmaf(xr, wi.y, v[1][1]);
        v[1][2] = fmaf(xr, wi.z, v[1][2]); v[1][3] = fmaf(xr, wi.w, v[1][3]);
        v[2][0] = fmaf(xi, wr.x, v[2][0]); v[2][1] = fmaf(xi, wr.y, v[2][1]);
        v[2][2] = fmaf(xi, wr.z, v[2][2]); v[2][3] = fmaf(xi, wr.w, v[2][3]);
        v[3][0] = fmaf(xi, wi.x, v[3][0]); v[3][1] = fmaf(xi, wi.y, v[3][1]);
        v[3][2] = fmaf(xi, wi.z, v[3][2]); v[3][3] = fmaf(xi, wi.w, v[3][3]);
    }
    const int rowg = rt * 32 + row;
#pragma unroll
    for (int k = 0; k < 4; ++k) {
        float* o = Vout + (unsigned)k * 524288u + (hn * ROWS + rowg) * 64 + eh * 32 + eq * 4;
        *(float4*)o = make_float4(v[k][0], v[k][1], v[k][2], v[k][3]);
    }
    if (eh == 0 && t < 32) {
        const int rw = t;
        float cr = 0.f, ci = 0.f;
        for (int d = 0; d < 64; ++d) {
            float br = Abr[h * 64 + d], bi = Abi[h * 64 + d];
            float bm = br - bi, bp = br + bi;
            float xr = sX[0][d * 32 + ((rw + d) & 31)];
            float xi = sX[1][d * 32 + ((rw + d) & 31)];
            cr = fmaf(bm, xr, fmaf(-bp, xi, cr));
            ci = fmaf(bm, xi, fmaf( bp, xr, ci));
        }
        cR[hn * ROWS + rt * 32 + rw] = cr;
        cI[hn * ROWS + rt * 32 + rw] = ci;
    }
}

// ---------------------------------------------------------------------------
// K4: AC scores. grid (16 = qt(8) + 8*ph(2), 16 hn, 4 b), block 256
// ---------------------------------------------------------------------------
__global__ __launch_bounds__(256) void k_ac(
    const float* __restrict__ wqr, const float* __restrict__ wqi,
    const float* __restrict__ wkr, const float* __restrict__ wki,
    const float* __restrict__ mu,  const float* __restrict__ rs,
    const float* __restrict__ gwr, const float* __restrict__ btwr,
    const float* __restrict__ gwi, const float* __restrict__ btwi,
    float* __restrict__ ACr, float* __restrict__ ACi)
{
    __shared__ float sK[2][64][65];
    __shared__ float sQT[2][64][20];   // [d][16 q + pad]
    const int t = threadIdx.x;
    const int bx = blockIdx.x, qt = bx & 7, ph = bx >> 3;
    const int hn = blockIdx.y, h = hn >> 1;
    const int b = blockIdx.z;
    const float* mu2 = mu + (32 + hn) * 64; const float* rs2 = rs + (32 + hn) * 64;
    const float* mu3 = mu + (48 + hn) * 64; const float* rs3 = rs + (48 + hn) * 64;
#pragma unroll
    for (int j = 0; j < 4; ++j) {
        int flat4 = t + 256 * j;
        int word = flat4 * 4;
        int pp = word >> 6, ee = word & 63;
        int gidx = (hn * ROWS + (ph * 64 + pp) * 4 + b) * 64 + ee;
        float4 kr = *(const float4*)&wkr[gidx];
        float4 ki = *(const float4*)&wki[gidx];
        float4 m2 = *(const float4*)&mu2[ee]; float4 r2 = *(const float4*)&rs2[ee];
        float4 m3 = *(const float4*)&mu3[ee]; float4 r3 = *(const float4*)&rs3[ee];
        sK[0][pp][ee+0] = (kr.x - m2.x) * r2.x; sK[0][pp][ee+1] = (kr.y - m2.y) * r2.y;
        sK[0][pp][ee+2] = (kr.z - m2.z) * r2.z; sK[0][pp][ee+3] = (kr.w - m2.w) * r2.w;
        sK[1][pp][ee+0] = (ki.x - m3.x) * r3.x; sK[1][pp][ee+1] = (ki.y - m3.y) * r3.y;
        sK[1][pp][ee+2] = (ki.z - m3.z) * r3.z; sK[1][pp][ee+3] = (ki.w - m3.w) * r3.w;
    }
    const float* mu0 = mu + hn * 64;        const float* rs0 = rs + hn * 64;
    const float* mu1 = mu + (16 + hn) * 64; const float* rs1 = rs + (16 + hn) * 64;
    {
        int word = t * 4;
        int qq = word >> 6, dd = word & 63;          // qq 0..15
        int gidx = (hn * ROWS + (qt * 16 + qq) * 4 + b) * 64 + dd;
        float4 xr = *(const float4*)&wqr[gidx];
        float4 xi = *(const float4*)&wqi[gidx];
        float4 m0 = *(const float4*)&mu0[dd]; float4 r0 = *(const float4*)&rs0[dd];
        float4 m1 = *(const float4*)&mu1[dd]; float4 r1 = *(const float4*)&rs1[dd];
        float4 g0 = *(const float4*)&gwr[h * 64 + dd]; float4 b0 = *(const float4*)&btwr[h * 64 + dd];
        float4 g1 = *(const float4*)&gwi[h * 64 + dd]; float4 b1 = *(const float4*)&btwi[h * 64 + dd];
        sQT[0][dd+0][qq] = fmaf((xr.x - m0.x) * r0.x, g0.x, b0.x);
        sQT[0][dd+1][qq] = fmaf((xr.y - m0.y) * r0.y, g0.y, b0.y);
        sQT[0][dd+2][qq] = fmaf((xr.z - m0.z) * r0.z, g0.z, b0.z);
        sQT[0][dd+3][qq] = fmaf((xr.w - m0.w) * r0.w, g0.w, b0.w);
        sQT[1][dd+0][qq] = fmaf((xi.x - m1.x) * r1.x, g1.x, b1.x);
        sQT[1][dd+1][qq] = fmaf((xi.y - m1.y) * r1.y, g1.y, b1.y);
        sQT[1][dd+2][qq] = fmaf((xi.z - m1.z) * r1.z, g1.z, b1.z);
        sQT[1][dd+3][qq] = fmaf((xi.w - m1.w) * r1.w, g1.w, b1.w);
    }
    __syncthreads();
    const int p = t & 63, qs = t >> 6;
    float acr[4], aci[4];
#pragma unroll
    for (int j = 0; j < 4; ++j) { acr[j] = 0.f; aci[j] = 0.f; }
    for (int e = 0; e < 64; ++e) {
        float kr = sK[0][p][e], ki = sK[1][p][e];
        float4 qr = *(const float4*)&sQT[0][e][qs * 4];
        float4 qi = *(const float4*)&sQT[1][e][qs * 4];
        acr[0] = fmaf(kr, qr.x, fmaf(-ki, qi.x, acr[0]));
        acr[1] = fmaf(kr, qr.y, fmaf(-ki, qi.y, acr[1]));
        acr[2] = fmaf(kr, qr.z, fmaf(-ki, qi.z, acr[2]));
        acr[3] = fmaf(kr, qr.w, fmaf(-ki, qi.w, acr[3]));
        aci[0] = fmaf(kr, qi.x, fmaf( ki, qr.x, aci[0]));
        aci[1] = fmaf(kr, qi.y, fmaf( ki, qr.y, aci[1]));
        aci[2] = fmaf(kr, qi.z, fmaf( ki, qr.z, aci[2]));
        aci[3] = fmaf(kr, qi.w, fmaf( ki, qr.w, aci[3]));
    }
#pragma unroll
    for (int j = 0; j < 4; ++j) {
        int q = qt * 16 + qs * 4 + j;
        int oidx = ((hn * 128 + q) * 4 + b) * 128 + ph * 64 + p;
        ACr[oidx] = acr[j];
        ACi[oidx] = aci[j];
    }
}

// ---------------------------------------------------------------------------
// K5 v6: fused BD + AC + affinity + softmax.  wave = b, lane = (eo 16, pl 4).
// Vv staged in LDS with 20-float eo-stride (2-way bank aliasing = free).
// NO occupancy hint (v5's (256,3) caused 84-VGPR spills -> 534 MB scratch).
// grid (256 nq, 8 pq).
// ---------------------------------------------------------------------------
__global__ __launch_bounds__(256) void k_bd(
    const float* __restrict__ ER, const float* __restrict__ EI,
    const float* __restrict__ Vv, const float* __restrict__ cR, const float* __restrict__ cI,
    const float* __restrict__ ACr, const float* __restrict__ ACi,
    float* __restrict__ AFF)
{
    // main phase: sVv [b][h][eo][k][4] stride 20/eo -> (b*8+h)*320 + eo*20 + k*4  (10240 f)
    // epilogue:   reused as 4 x 2176 transpose scratch (8704 f <= 10240)
    __shared__ __align__(16) float uS[10240];
    __shared__ float sL[128 * 5];            // logits [c][b]
    const int t = threadIdx.x;
    const int w = t >> 6;            // wave = b
    const int l = t & 63;
    const int eo = l & 15, pl = l >> 4;
    const int nq = blockIdx.x;
    const int pq = blockIdx.y;
    const int n = nq >> 7, q = nq & 127;
    const int P0 = pq * 16;

    // ---- stage Vv: 4096 float4 loads, coalesced; padded LDS layout ----
#pragma unroll
    for (int it = 0; it < 8; ++it) {
        int flat = t + 256 * it;                 // float4 units
        int e4 = flat & 15, k = (flat >> 4) & 3, h = (flat >> 6) & 7, bb = flat >> 9;
        float4 x = *(const float4*)&Vv[(unsigned)k * 524288u
                                       + ((h * 2 + n) * ROWS + q * 4 + bb) * 64u + e4 * 4];
        *(float4*)&uS[(bb * 8 + h) * 320 + e4 * 20 + k * 4] = x;
    }
    __syncthreads();

    float accr[8][4], acci[8][4];
#pragma unroll
    for (int h = 0; h < 8; ++h)
#pragma unroll
        for (int j = 0; j < 4; ++j) { accr[h][j] = 0.f; acci[h][j] = 0.f; }

#pragma unroll
    for (int jc = 0; jc < 2; ++jc) {
        float4 A[2], Bv[2], C4[2], D4[2];
#pragma unroll
        for (int jj = 0; jj < 2; ++jj) {
            int j = jc * 2 + jj;
            int p = P0 + pl * 4 + j;
            int qpo = (((n * 128 + q) * 128 + p) * 4 + w) * 64 + eo * 4;
            int pqo = (((n * 128 + p) * 128 + q) * 4 + w) * 64 + eo * 4;
            A[jj]  = *(const float4*)(ER + qpo);
            Bv[jj] = *(const float4*)(EI + qpo);
            C4[jj] = *(const float4*)(ER + pqo);
            D4[jj] = *(const float4*)(EI + pqo);
        }
#pragma unroll
        for (int h = 0; h < 8; ++h) {
            const float* vb = &uS[(w * 8 + h) * 320 + eo * 20];
            float4 v1 = *(const float4*)(vb);
            float4 v2 = *(const float4*)(vb + 4);
            float4 v3 = *(const float4*)(vb + 8);
            float4 v4 = *(const float4*)(vb + 12);
#pragma unroll
            for (int jj = 0; jj < 2; ++jj) {
                int j = jc * 2 + jj;
                DOT4 (accr[h][j], A[jj],  v1);
                NDOT4(accr[h][j], Bv[jj], v2);
                NDOT4(accr[h][j], C4[jj], v4);
                NDOT4(accr[h][j], D4[jj], v3);
                DOT4 (acci[h][j], A[jj],  v3);
                NDOT4(acci[h][j], Bv[jj], v4);
                DOT4 (acci[h][j], C4[jj], v2);
                DOT4 (acci[h][j], D4[jj], v1);
            }
        }
    }

    // Output assignments: lane l handles c1 = l (h 0..3) and c2 = l+64 (h 4..7)
    const int c1 = l, c2 = l + 64;
    const int h1 = c1 >> 4, h2 = h1 + 4;
    const int pc = c1 & 15;
    const int jr = pc >> 2, plr = pc & 3;
    const int poff = plr * 4 + jr;
    // prefetch AC + c (L2-hot, latency overlaps LDS reduction)
    float ac_r1 = ACr[(((h1 * 2 + n) * 128 + q) * 4 + w) * 128 + P0 + poff];
    float ac_i1 = ACi[(((h1 * 2 + n) * 128 + q) * 4 + w) * 128 + P0 + poff];
    float ac_r2 = ACr[(((h2 * 2 + n) * 128 + q) * 4 + w) * 128 + P0 + poff];
    float ac_i2 = ACi[(((h2 * 2 + n) * 128 + q) * 4 + w) * 128 + P0 + poff];
    float cr1 = cR[(h1 * 2 + n) * ROWS + q * 4 + w];
    float ci1 = cI[(h1 * 2 + n) * ROWS + q * 4 + w];
    float cr2 = cR[(h2 * 2 + n) * ROWS + q * 4 + w];
    float ci2 = cI[(h2 * 2 + n) * ROWS + q * 4 + w];

    __syncthreads();                  // Vv region dead -> safe to reuse as scratch
    float* wb = uS + w * 2176;
    // ---- r pass ----
#pragma unroll
    for (int h = 0; h < 8; ++h)
#pragma unroll
        for (int j = 0; j < 4; ++j)
            wb[(h * 16 + j * 4 + pl) * 17 + eo] = accr[h][j];
    __syncthreads();
    float bdr1 = 0.f, bdr2 = 0.f;
#pragma unroll
    for (int i = 0; i < 16; ++i) {
        bdr1 += wb[c1 * 17 + i];
        bdr2 += wb[c2 * 17 + i];
    }
    __syncthreads();
    // ---- i pass ----
#pragma unroll
    for (int h = 0; h < 8; ++h)
#pragma unroll
        for (int j = 0; j < 4; ++j)
            wb[(h * 16 + j * 4 + pl) * 17 + eo] = acci[h][j];
    __syncthreads();
    float bdi1 = 0.f, bdi2 = 0.f;
#pragma unroll
    for (int i = 0; i < 16; ++i) {
        bdi1 += wb[c1 * 17 + i];
        bdi2 += wb[c2 * 17 + i];
    }

    bdr1 += cr1; bdi1 += ci1;
    bdr2 += cr2; bdi2 += ci2;
    float aff1 = sqrtf(fmaf(ac_r1, ac_r1, ac_i1 * ac_i1)) + sqrtf(fmaf(bdr1, bdr1, bdi1 * bdi1));
    float aff2 = sqrtf(fmaf(ac_r2, ac_r2, ac_i2 * ac_i2)) + sqrtf(fmaf(bdr2, bdr2, bdi2 * bdi2));
    float lg1 = aff1 * TEMPER, lg2 = aff2 * TEMPER;
    sL[c1 * 5 + w] = lg1;
    sL[c2 * 5 + w] = lg2;
    __syncthreads();
    {
        float l0 = sL[c1 * 5 + 0], l1x = sL[c1 * 5 + 1], l2x = sL[c1 * 5 + 2], l3x = sL[c1 * 5 + 3];
        float m = fmaxf(fmaxf(l0, l1x), fmaxf(l2x, l3x));
        float s = __expf(l0 - m) + __expf(l1x - m) + __expf(l2x - m) + __expf(l3x - m);
        AFF[(unsigned)((nq * 4 + w) * 8 + h1) * 128 + P0 + poff] = __expf(lg1 - m) / s;
    }
    {
        float l0 = sL[c2 * 5 + 0], l1x = sL[c2 * 5 + 1], l2x = sL[c2 * 5 + 2], l3x = sL[c2 * 5 + 3];
        float m = fmaxf(fmaxf(l0, l1x), fmaxf(l2x, l3x));
        float s = __expf(l0 - m) + __expf(l1x - m) + __expf(l2x - m) + __expf(l3x - m);
        AFF[(unsigned)((nq * 4 + w) * 8 + h2) * 128 + P0 + poff] = __expf(lg2 - m) / s;
    }
}

// ---------------------------------------------------------------------------
// K6 v2: PV contraction. AFF layout [n][q][b][h][p].
// grid 1024, block 256
// ---------------------------------------------------------------------------
__global__ __launch_bounds__(256) void k_pv(
    const float* __restrict__ AFF,
    const float* __restrict__ Vr, const float* __restrict__ Vi,
    float* __restrict__ out)
{
    __shared__ float sA[8 * 132];
    __shared__ float sRed[4 * 1092];
    const int t = threadIdx.x;
    const int nqb = blockIdx.x;
    const int b = nqb & 3, q = (nqb >> 2) & 127, n = nqb >> 9;
#pragma unroll
    for (int j = 0; j < 4; ++j) {
        int idx = t + 256 * j;
        sA[(idx >> 7) * 132 + (idx & 127)] = AFF[(unsigned)nqb * 1024u + idx];
    }
    __syncthreads();
    const int d = t & 63, pp = t >> 6;
    const float* vr = Vr + (n * 512 + b) * 64 + d;
    const float* vi = Vi + (n * 512 + b) * 64 + d;
    float oR[8], oI[8];
#pragma unroll
    for (int h = 0; h < 8; ++h) { oR[h] = 0.f; oI[h] = 0.f; }
    for (int pz = 0; pz < 32; ++pz) {
        int p = pp * 32 + pz;
        float xr = vr[p * 256];
        float xi = vi[p * 256];
#pragma unroll
        for (int h = 0; h < 8; ++h) {
            float a = sA[h * 132 + p];
            oR[h] = fmaf(a, xr, oR[h]);
            oI[h] = fmaf(a, xi, oI[h]);
        }
    }
    float* wb = sRed + pp * 1092;
#pragma unroll
    for (int s = 0; s < 16; ++s) {
        int h = s >> 1;
        wb[d * 17 + s] = (s & 1) ? oI[h] : oR[h];
    }
    __syncthreads();
    const int d2 = t & 63, g = t >> 6;
#pragma unroll
    for (int k = 0; k < 4; ++k) {
        int s = g * 4 + k;
        float v = sRed[0 * 1092 + d2 * 17 + s] + sRed[1 * 1092 + d2 * 17 + s]
                + sRed[2 * 1092 + d2 * 17 + s] + sRed[3 * 1092 + d2 * 17 + s];
        int h = s >> 1, ri = s & 1;
        out[(unsigned)ri * 524288u + ((n * 128 + q) * 4 + b) * 512u + h * 64 + d2] = v;
    }
}

// ---------------------------------------------------------------------------
extern "C" void kernel_launch(void* const* d_in, const int* in_sizes, int n_in,
                              void* d_out, int out_size, void* d_ws, size_t ws_size,
                              hipStream_t stream) {
    (void)in_sizes; (void)n_in; (void)out_size; (void)ws_size;
    const float* q_r  = (const float*)d_in[0];
    const float* q_i  = (const float*)d_in[1];
    const float* k_r  = (const float*)d_in[2];
    const float* k_i  = (const float*)d_in[3];
    const float* v_r  = (const float*)d_in[4];
    const float* v_i  = (const float*)d_in[5];
    const float* e_r  = (const float*)d_in[6];
    const float* e_i  = (const float*)d_in[7];
    const float* WKr_w  = (const float*)d_in[8];
    const float* WKi_w  = (const float*)d_in[10];
    const float* WKRr_w = (const float*)d_in[12];
    const float* WKRr_b = (const float*)d_in[13];
    const float* WKRi_w = (const float*)d_in[14];
    const float* WKRi_b = (const float*)d_in[15];
    const float* WQr_w  = (const float*)d_in[16];
    const float* WQi_w  = (const float*)d_in[18];
    const float* ww_r_g  = (const float*)d_in[20];
    const float* ww_r_bt = (const float*)d_in[21];
    const float* ww_i_g  = (const float*)d_in[22];
    const float* ww_i_bt = (const float*)d_in[23];
    const float* wr_r_g  = (const float*)d_in[24];
    const float* wr_r_bt = (const float*)d_in[25];
    const float* wr_i_g  = (const float*)d_in[26];
    const float* wr_i_bt = (const float*)d_in[27];
    float* ws  = (float*)d_ws;
    float* out = (float*)d_out;

    k_proj<<<dim3(16, 16, 2), 256, 0, stream>>>(q_r, q_i, k_r, k_i,
                                                WQr_w, WQi_w, WKr_w, WKi_w, ws);
    k_stats1<<<256, 256, 0, stream>>>(ws + WQ_R, ws + PART_);
    k_stats2<<<64, 64, 0, stream>>>(ws + PART_, ws + MU_, ws + RS_);
    k_vvec<<<dim3(32, 16), 256, 0, stream>>>(ws + WQ_R, ws + WQ_I, ws + MU_, ws + RS_,
                                             WKRr_w, WKRi_w, WKRr_b, WKRi_b,
                                             wr_r_g, wr_r_bt, wr_i_g, wr_i_bt,
                                             ws + VV_, ws + C_R_, ws + C_I_);
    k_ac<<<dim3(16, 16, 4), 256, 0, stream>>>(ws + WQ_R, ws + WQ_I, ws + WK_R, ws + WK_I,
                                              ws + MU_, ws + RS_,
                                              ww_r_g, ww_r_bt, ww_i_g, ww_i_bt,
                                              ws + ACR_, ws + ACI_);
    k_bd<<<dim3(256, 8), 256, 0, stream>>>(e_r, e_i, ws + VV_, ws + C_R_, ws + C_I_,
                                           ws + ACR_, ws + ACI_, ws + AFF_);
    k_pv<<<1024, 256, 0, stream>>>(ws + AFF_, v_r, v_i, out);
}

// Round 7
// 218.942 us; speedup vs baseline: 2.0525x; 1.1421x over previous
//
#include <hip/hip_runtime.h>
#include <math.h>

// Problem constants
#define NH 8
#define DDIM 64
#define NN 2
#define QQ 128
#define PPDIM 128
#define BBD 4
#define ROWS 512           // Q*B == P*B
#define EPSN 1e-5f
#define TEMPER 30.0f

// Workspace layout (float offsets)
#define WQ_R 0u            // [H][N][512][64] rows = q*4+b
#define WQ_I 524288u
#define WK_R 1048576u      // rows = p*4+b
#define WK_I 1572864u
#define VV_  2105344u      // 4 x [H][N][512][64]  (v1,v2,v3,v4)
#define C_R_ 4202496u      // [H][N][512]
#define C_I_ 4210688u
#define ACR_ 4218880u      // [H][N][Q][B][P]
#define ACI_ 5267456u
#define AFF_ 6316032u      // [N][Q][B][H][P]
// stats partials live in AFF region (dead until k_bd): [grp 64][sv 2][rt 16][d 64]
#define PART_ AFF_

#define DOT4(acc, s, v)  { acc = fmaf((s).x,(v).x,acc); acc = fmaf((s).y,(v).y,acc); acc = fmaf((s).z,(v).z,acc); acc = fmaf((s).w,(v).w,acc); }
#define NDOT4(acc, s, v) { acc = fmaf(-(s).x,(v).x,acc); acc = fmaf(-(s).y,(v).y,acc); acc = fmaf(-(s).z,(v).z,acc); acc = fmaf(-(s).w,(v).w,acc); }

// ---------------------------------------------------------------------------
// K1: complex projection (pre-norm) + fused InstanceNorm partial stats.
// grid (16 rowtiles, 16 hn, 2 qk), block 256
// ---------------------------------------------------------------------------
__global__ __launch_bounds__(256) void k_proj(
    const float* __restrict__ qR, const float* __restrict__ qI,
    const float* __restrict__ kR, const float* __restrict__ kI,
    const float* __restrict__ WQr, const float* __restrict__ WQi,
    const float* __restrict__ WKr, const float* __restrict__ WKi,
    float* __restrict__ ws, float* __restrict__ part)
{
    __shared__ __align__(16) float sWT[2][64 * 64];     // transposed: [e][d]
    const int t  = threadIdx.x;
    const int rt = blockIdx.x;
    const int hn = blockIdx.y;
    const int z  = blockIdx.z;
    const int h = hn >> 1, n = hn & 1;
    const float* inR = z ? kR : qR;
    const float* inI = z ? kI : qI;
    const float* wr0 = (z ? WKr : WQr) + h * 4096;
    const float* wi0 = (z ? WKi : WQi) + h * 4096;
    float* outR = ws + (z ? WK_R : WQ_R);
    float* outI = ws + (z ? WK_I : WQ_I);
#pragma unroll
    for (int j = 0; j < 16; ++j) {
        int flat = t + 256 * j;
        int d = flat & 63, e = flat >> 6;
        sWT[0][e * 64 + d] = wr0[d * 64 + e];
        sWT[1][e * 64 + d] = wi0[d * 64 + e];
    }
    __syncthreads();
    const int row = t & 31, dq = t >> 5;     // dq 0..7, 8 outputs/thread
    const int rowg = rt * 32 + row;
    const float4* xr4 = (const float4*)(inR + (n * ROWS + rowg) * 64);
    const float4* xi4 = (const float4*)(inI + (n * ROWS + rowg) * 64);
    float ar[8], ai[8];
#pragma unroll
    for (int j = 0; j < 8; ++j) { ar[j] = 0.f; ai[j] = 0.f; }
    for (int ec = 0; ec < 16; ++ec) {
        float4 xrv = xr4[ec], xiv = xi4[ec];
        float xrs[4] = {xrv.x, xrv.y, xrv.z, xrv.w};
        float xis[4] = {xiv.x, xiv.y, xiv.z, xiv.w};
#pragma unroll
        for (int u = 0; u < 4; ++u) {
            int e = ec * 4 + u;
            const float4* wrp = (const float4*)&sWT[0][e * 64 + dq * 8];
            const float4* wip = (const float4*)&sWT[1][e * 64 + dq * 8];
            float xr = xrs[u], xi = xis[u];
#pragma unroll
            for (int j4 = 0; j4 < 2; ++j4) {
                float4 wr = wrp[j4], wi = wip[j4];
                ar[j4*4+0] = fmaf(xr, wr.x, fmaf(-xi, wi.x, ar[j4*4+0]));
                ar[j4*4+1] = fmaf(xr, wr.y, fmaf(-xi, wi.y, ar[j4*4+1]));
                ar[j4*4+2] = fmaf(xr, wr.z, fmaf(-xi, wi.z, ar[j4*4+2]));
                ar[j4*4+3] = fmaf(xr, wr.w, fmaf(-xi, wi.w, ar[j4*4+3]));
                ai[j4*4+0] = fmaf(xr, wi.x, fmaf( xi, wr.x, ai[j4*4+0]));
                ai[j4*4+1] = fmaf(xr, wi.y, fmaf( xi, wr.y, ai[j4*4+1]));
                ai[j4*4+2] = fmaf(xr, wi.z, fmaf( xi, wr.z, ai[j4*4+2]));
                ai[j4*4+3] = fmaf(xr, wi.w, fmaf( xi, wr.w, ai[j4*4+3]));
            }
        }
    }
    float* oR = outR + ((unsigned)hn * ROWS + rowg) * 64 + dq * 8;
    float* oI = outI + ((unsigned)hn * ROWS + rowg) * 64 + dq * 8;
#pragma unroll
    for (int j4 = 0; j4 < 2; ++j4) {
        ((float4*)oR)[j4] = make_float4(ar[j4*4+0], ar[j4*4+1], ar[j4*4+2], ar[j4*4+3]);
        ((float4*)oI)[j4] = make_float4(ai[j4*4+0], ai[j4*4+1], ai[j4*4+2], ai[j4*4+3]);
    }
    // ---- fused stats partials: sum over this block's 32 rows (lanes 0..31 of
    // each 32-lane half; xor masks 1..16 stay within the half) ----
    float s_r[8], q_r8[8], s_i[8], q_i8[8];
#pragma unroll
    for (int i = 0; i < 8; ++i) {
        s_r[i] = ar[i]; q_r8[i] = ar[i] * ar[i];
        s_i[i] = ai[i]; q_i8[i] = ai[i] * ai[i];
    }
#pragma unroll
    for (int m = 1; m <= 16; m <<= 1) {
#pragma unroll
        for (int i = 0; i < 8; ++i) {
            s_r[i]  += __shfl_xor(s_r[i],  m);
            q_r8[i] += __shfl_xor(q_r8[i], m);
            s_i[i]  += __shfl_xor(s_i[i],  m);
            q_i8[i] += __shfl_xor(q_i8[i], m);
        }
    }
    if ((t & 31) == 0) {
        const int gr = (z * 2) * 16 + hn;        // out_r tensor group
        const int gi = (z * 2 + 1) * 16 + hn;    // out_i tensor group
#pragma unroll
        for (int i = 0; i < 8; ++i) {
            int d = dq * 8 + i;
            part[(unsigned)gr * 2048u + rt * 64 + d]          = s_r[i];
            part[(unsigned)gr * 2048u + 1024 + rt * 64 + d]   = q_r8[i];
            part[(unsigned)gi * 2048u + rt * 64 + d]          = s_i[i];
            part[(unsigned)gi * 2048u + 1024 + rt * 64 + d]   = q_i8[i];
        }
    }
}

// ---------------------------------------------------------------------------
// K3: v-vectors + bias dots.  Stats finalized in prologue from partials.
// Lane map (eq fast, row slow) -> coalesced full-line stores.
// grid (32 = rt(16) + 16*eh(2), 16 hn), block 256
// ---------------------------------------------------------------------------
__global__ __launch_bounds__(256) void k_vvec(
    const float* __restrict__ wqr, const float* __restrict__ wqi,
    const float* __restrict__ part,
    const float* __restrict__ Ar,  const float* __restrict__ Ai,
    const float* __restrict__ Abr, const float* __restrict__ Abi,
    const float* __restrict__ gr,  const float* __restrict__ btr,
    const float* __restrict__ gi,  const float* __restrict__ bti,
    float* __restrict__ Vout, float* __restrict__ cR, float* __restrict__ cI)
{
    __shared__ __align__(16) float sW[2][2048];   // [d 64][e'_half 32]
    __shared__ float sX[2][2048];                 // swizzled [d 64][row 32]
    __shared__ float sMu[2][64], sRs[2][64];
    const int t = threadIdx.x;
    const int bx = blockIdx.x, rt = bx & 15, eh = bx >> 4;
    const int hn = blockIdx.y, h = hn >> 1;
    // ---- finalize stats for groups hn (wq_r) and 16+hn (wq_i) ----
    if (t < 128) {
        int g = t >> 6, d = t & 63;
        int grp = (g ? 16 : 0) + hn;
        const float* ps = part + (unsigned)grp * 2048u + d;
        float s = 0.f, qq = 0.f;
#pragma unroll
        for (int r2 = 0; r2 < 16; ++r2) {
            s  += ps[r2 * 64];
            qq += ps[1024 + r2 * 64];
        }
        float m = s * (1.f / 512.f);
        float var = qq * (1.f / 512.f) - m * m;
        sMu[g][d] = m;
        sRs[g][d] = rsqrtf(var + EPSN);
    }
    const float* a0 = Ar + h * 4096;
    const float* a1 = Ai + h * 4096;
#pragma unroll
    for (int j = 0; j < 8; ++j) {
        int flat = t + 256 * j;
        int c = flat & 31, r = flat >> 5;
        sW[0][r * 32 + c] = a0[r * 64 + eh * 32 + c];
        sW[1][r * 32 + c] = a1[r * 64 + eh * 32 + c];
    }
    __syncthreads();
    {
        const int d = t & 63;
        const float m0 = sMu[0][d], r0 = sRs[0][d], g0 = gr[h * 64 + d], b0 = btr[h * 64 + d];
        const float m1 = sMu[1][d], r1 = sRs[1][d], g1 = gi[h * 64 + d], b1 = bti[h * 64 + d];
#pragma unroll
        for (int j = 0; j < 8; ++j) {
            int row = (t >> 6) + 4 * j;  // 0..31
            int gidx = (hn * ROWS + rt * 32 + row) * 64 + d;
            float xr = wqr[gidx], xi = wqi[gidx];
            sX[0][d * 32 + ((row + d) & 31)] = (xr - m0) * r0 * g0 + b0;
            sX[1][d * 32 + ((row + d) & 31)] = (xi - m1) * r1 * g1 + b1;
        }
    }
    __syncthreads();
    const int eq = t & 7, row = t >> 3;   // eq fast -> coalesced stores
    float v[4][4];
#pragma unroll
    for (int k = 0; k < 4; ++k)
#pragma unroll
        for (int j = 0; j < 4; ++j) v[k][j] = 0.f;
    for (int d = 0; d < 64; ++d) {
        float xr = sX[0][d * 32 + ((row + d) & 31)];
        float xi = sX[1][d * 32 + ((row + d) & 31)];
        float4 wr = *(const float4*)&sW[0][d * 32 + eq * 4];
        float4 wi = *(const float4*)&sW[1][d * 32 + eq * 4];
        v[0][0] = fmaf(xr, wr.x, v[0][0]); v[0][1] = fmaf(xr, wr.y, v[0][1]);
        v[0][2] = fmaf(xr, wr.z, v[0][2]); v[0][3] = fmaf(xr, wr.w, v[0][3]);
        v[1][0] = fmaf(xr, wi.x, v[1][0]); v[1][1] = fmaf(xr, wi.y, v[1][1]);
        v[1][2] = fmaf(xr, wi.z, v[1][2]); v[1][3] = fmaf(xr, wi.w, v[1][3]);
        v[2][0] = fmaf(xi, wr.x, v[2][0]); v[2][1] = fmaf(xi, wr.y, v[2][1]);
        v[2][2] = fmaf(xi, wr.z, v[2][2]); v[2][3] = fmaf(xi, wr.w, v[2][3]);
        v[3][0] = fmaf(xi, wi.x, v[3][0]); v[3][1] = fmaf(xi, wi.y, v[3][1]);
        v[3][2] = fmaf(xi, wi.z, v[3][2]); v[3][3] = fmaf(xi, wi.w, v[3][3]);
    }
    const int rowg = rt * 32 + row;
#pragma unroll
    for (int k = 0; k < 4; ++k) {
        float* o = Vout + (unsigned)k * 524288u + (hn * ROWS + rowg) * 64 + eh * 32 + eq * 4;
        *(float4*)o = make_float4(v[k][0], v[k][1], v[k][2], v[k][3]);
    }
    if (eh == 0 && t < 32) {
        const int rw = t;
        float cr = 0.f, ci = 0.f;
        for (int d = 0; d < 64; ++d) {
            float br = Abr[h * 64 + d], bi = Abi[h * 64 + d];
            float bm = br - bi, bp = br + bi;
            float xr = sX[0][d * 32 + ((rw + d) & 31)];
            float xi = sX[1][d * 32 + ((rw + d) & 31)];
            cr = fmaf(bm, xr, fmaf(-bp, xi, cr));
            ci = fmaf(bm, xi, fmaf( bp, xr, ci));
        }
        cR[hn * ROWS + rt * 32 + rw] = cr;
        cI[hn * ROWS + rt * 32 + rw] = ci;
    }
}

// ---------------------------------------------------------------------------
// K4: AC scores.  Stats finalized in prologue.
// grid (16 = qt(8) + 8*ph(2), 16 hn, 4 b), block 256
// ---------------------------------------------------------------------------
__global__ __launch_bounds__(256) void k_ac(
    const float* __restrict__ wqr, const float* __restrict__ wqi,
    const float* __restrict__ wkr, const float* __restrict__ wki,
    const float* __restrict__ part,
    const float* __restrict__ gwr, const float* __restrict__ btwr,
    const float* __restrict__ gwi, const float* __restrict__ btwi,
    float* __restrict__ ACr, float* __restrict__ ACi)
{
    __shared__ float sK[2][64][65];
    __shared__ float sQT[2][64][20];   // [d][16 q + pad]
    __shared__ __align__(16) float sMu[4][64], sRs[4][64];
    const int t = threadIdx.x;
    const int bx = blockIdx.x, qt = bx & 7, ph = bx >> 3;
    const int hn = blockIdx.y, h = hn >> 1;
    const int b = blockIdx.z;
    // ---- finalize stats for all 4 tensor groups ----
    {
        int g = t >> 6, d = t & 63;
        int grp = g * 16 + hn;
        const float* ps = part + (unsigned)grp * 2048u + d;
        float s = 0.f, qq = 0.f;
#pragma unroll
        for (int r2 = 0; r2 < 16; ++r2) {
            s  += ps[r2 * 64];
            qq += ps[1024 + r2 * 64];
        }
        float m = s * (1.f / 512.f);
        float var = qq * (1.f / 512.f) - m * m;
        sMu[g][d] = m;
        sRs[g][d] = rsqrtf(var + EPSN);
    }
    __syncthreads();
#pragma unroll
    for (int j = 0; j < 4; ++j) {
        int flat4 = t + 256 * j;
        int word = flat4 * 4;
        int pp = word >> 6, ee = word & 63;
        int gidx = (hn * ROWS + (ph * 64 + pp) * 4 + b) * 64 + ee;
        float4 kr = *(const float4*)&wkr[gidx];
        float4 ki = *(const float4*)&wki[gidx];
        float4 m2 = *(const float4*)&sMu[2][ee]; float4 r2 = *(const float4*)&sRs[2][ee];
        float4 m3 = *(const float4*)&sMu[3][ee]; float4 r3 = *(const float4*)&sRs[3][ee];
        sK[0][pp][ee+0] = (kr.x - m2.x) * r2.x; sK[0][pp][ee+1] = (kr.y - m2.y) * r2.y;
        sK[0][pp][ee+2] = (kr.z - m2.z) * r2.z; sK[0][pp][ee+3] = (kr.w - m2.w) * r2.w;
        sK[1][pp][ee+0] = (ki.x - m3.x) * r3.x; sK[1][pp][ee+1] = (ki.y - m3.y) * r3.y;
        sK[1][pp][ee+2] = (ki.z - m3.z) * r3.z; sK[1][pp][ee+3] = (ki.w - m3.w) * r3.w;
    }
    {
        int word = t * 4;
        int qq = word >> 6, dd = word & 63;          // qq 0..15
        int gidx = (hn * ROWS + (qt * 16 + qq) * 4 + b) * 64 + dd;
        float4 xr = *(const float4*)&wqr[gidx];
        float4 xi = *(const float4*)&wqi[gidx];
        float4 m0 = *(const float4*)&sMu[0][dd]; float4 r0 = *(const float4*)&sRs[0][dd];
        float4 m1 = *(const float4*)&sMu[1][dd]; float4 r1 = *(const float4*)&sRs[1][dd];
        float4 g0 = *(const float4*)&gwr[h * 64 + dd]; float4 b0 = *(const float4*)&btwr[h * 64 + dd];
        float4 g1 = *(const float4*)&gwi[h * 64 + dd]; float4 b1 = *(const float4*)&btwi[h * 64 + dd];
        sQT[0][dd+0][qq] = fmaf((xr.x - m0.x) * r0.x, g0.x, b0.x);
        sQT[0][dd+1][qq] = fmaf((xr.y - m0.y) * r0.y, g0.y, b0.y);
        sQT[0][dd+2][qq] = fmaf((xr.z - m0.z) * r0.z, g0.z, b0.z);
        sQT[0][dd+3][qq] = fmaf((xr.w - m0.w) * r0.w, g0.w, b0.w);
        sQT[1][dd+0][qq] = fmaf((xi.x - m1.x) * r1.x, g1.x, b1.x);
        sQT[1][dd+1][qq] = fmaf((xi.y - m1.y) * r1.y, g1.y, b1.y);
        sQT[1][dd+2][qq] = fmaf((xi.z - m1.z) * r1.z, g1.z, b1.z);
        sQT[1][dd+3][qq] = fmaf((xi.w - m1.w) * r1.w, g1.w, b1.w);
    }
    __syncthreads();
    const int p = t & 63, qs = t >> 6;
    float acr[4], aci[4];
#pragma unroll
    for (int j = 0; j < 4; ++j) { acr[j] = 0.f; aci[j] = 0.f; }
    for (int e = 0; e < 64; ++e) {
        float kr = sK[0][p][e], ki = sK[1][p][e];
        float4 qr = *(const float4*)&sQT[0][e][qs * 4];
        float4 qi = *(const float4*)&sQT[1][e][qs * 4];
        acr[0] = fmaf(kr, qr.x, fmaf(-ki, qi.x, acr[0]));
        acr[1] = fmaf(kr, qr.y, fmaf(-ki, qi.y, acr[1]));
        acr[2] = fmaf(kr, qr.z, fmaf(-ki, qi.z, acr[2]));
        acr[3] = fmaf(kr, qr.w, fmaf(-ki, qi.w, acr[3]));
        aci[0] = fmaf(kr, qi.x, fmaf( ki, qr.x, aci[0]));
        aci[1] = fmaf(kr, qi.y, fmaf( ki, qr.y, aci[1]));
        aci[2] = fmaf(kr, qi.z, fmaf( ki, qr.z, aci[2]));
        aci[3] = fmaf(kr, qi.w, fmaf( ki, qr.w, aci[3]));
    }
#pragma unroll
    for (int j = 0; j < 4; ++j) {
        int q = qt * 16 + qs * 4 + j;
        int oidx = ((hn * 128 + q) * 4 + b) * 128 + ph * 64 + p;
        ACr[oidx] = acr[j];
        ACi[oidx] = aci[j];
    }
}

// ---------------------------------------------------------------------------
// K5 v7: fused BD + AC + affinity + softmax.  wave = b, lane = (eo 16, pl 4),
// thread handles 2 p (p-tile 8 -> 4096 blocks).  Single 8-float4 emb burst,
// acc 32 regs -> ~110 VGPR, LDS exactly 40960 B -> 4 blocks/CU, 16 waves/CU.
// grid (256 nq, 16 pq).
// ---------------------------------------------------------------------------
__global__ __launch_bounds__(256) void k_bd(
    const float* __restrict__ ER, const float* __restrict__ EI,
    const float* __restrict__ Vv, const float* __restrict__ cR, const float* __restrict__ cI,
    const float* __restrict__ ACr, const float* __restrict__ ACi,
    float* __restrict__ AFF)
{
    // main: sVv [b][h][eo][k][4] (stride 20/eo) = 10240 f = 40960 B
    // epi:  scratch 4 x 1088 (0..4351) + logits at 4352..4671
    __shared__ __align__(16) float uS[10240];
    const int t = threadIdx.x;
    const int w = t >> 6;            // wave = b
    const int l = t & 63;
    const int eo = l & 15, pl = l >> 4;
    const int nq = blockIdx.x;
    const int pq = blockIdx.y;       // 0..15
    const int n = nq >> 7, q = nq & 127;
    const int P0 = pq * 8;

    // ---- stage Vv: 2048 float4, coalesced; padded layout ----
#pragma unroll
    for (int it = 0; it < 8; ++it) {
        int flat = t + 256 * it;                 // float4 units
        int e4 = flat & 15, k = (flat >> 4) & 3, h = (flat >> 6) & 7, bb = flat >> 9;
        float4 x = *(const float4*)&Vv[(unsigned)k * 524288u
                                       + ((h * 2 + n) * ROWS + q * 4 + bb) * 64u + e4 * 4];
        *(float4*)&uS[(bb * 8 + h) * 320 + e4 * 20 + k * 4] = x;
    }
    __syncthreads();

    // ---- single burst: 8 emb float4 loads ----
    float4 A[2], Bv[2], C4[2], D4[2];
#pragma unroll
    for (int jj = 0; jj < 2; ++jj) {
        int p = P0 + pl * 2 + jj;
        int qpo = (((n * 128 + q) * 128 + p) * 4 + w) * 64 + eo * 4;
        int pqo = (((n * 128 + p) * 128 + q) * 4 + w) * 64 + eo * 4;
        A[jj]  = *(const float4*)(ER + qpo);
        Bv[jj] = *(const float4*)(EI + qpo);
        C4[jj] = *(const float4*)(ER + pqo);
        D4[jj] = *(const float4*)(EI + pqo);
    }
    float accr[8][2], acci[8][2];
#pragma unroll
    for (int h = 0; h < 8; ++h)
#pragma unroll
        for (int j = 0; j < 2; ++j) { accr[h][j] = 0.f; acci[h][j] = 0.f; }
#pragma unroll
    for (int h = 0; h < 8; ++h) {
        const float* vb = &uS[(w * 8 + h) * 320 + eo * 20];
        float4 v1 = *(const float4*)(vb);
        float4 v2 = *(const float4*)(vb + 4);
        float4 v3 = *(const float4*)(vb + 8);
        float4 v4 = *(const float4*)(vb + 12);
#pragma unroll
        for (int jj = 0; jj < 2; ++jj) {
            DOT4 (accr[h][jj], A[jj],  v1);
            NDOT4(accr[h][jj], Bv[jj], v2);
            NDOT4(accr[h][jj], C4[jj], v4);
            NDOT4(accr[h][jj], D4[jj], v3);
            DOT4 (acci[h][jj], A[jj],  v3);
            NDOT4(acci[h][jj], Bv[jj], v4);
            DOT4 (acci[h][jj], C4[jj], v2);
            DOT4 (acci[h][jj], D4[jj], v1);
        }
    }

    // lane l owns chain c = l: h = l>>3, jj = (l&7)>>2, plr = l&3
    const int hh = l >> 3, rem = l & 7;
    const int jjr = rem >> 2, plr = rem & 3;
    const int poff = plr * 2 + jjr;
    float ac_r = ACr[(((hh * 2 + n) * 128 + q) * 4 + w) * 128 + P0 + poff];
    float ac_i = ACi[(((hh * 2 + n) * 128 + q) * 4 + w) * 128 + P0 + poff];
    float crx = cR[(hh * 2 + n) * ROWS + q * 4 + w];
    float cix = cI[(hh * 2 + n) * ROWS + q * 4 + w];

    __syncthreads();                  // Vv region dead -> reuse as scratch
    float* wb = uS + w * 1088;
    // ---- r pass ----
#pragma unroll
    for (int h = 0; h < 8; ++h)
#pragma unroll
        for (int jj = 0; jj < 2; ++jj)
            wb[(h * 8 + jj * 4 + pl) * 17 + eo] = accr[h][jj];
    __syncthreads();
    float bdr = 0.f;
#pragma unroll
    for (int i = 0; i < 16; ++i) bdr += wb[l * 17 + i];
    __syncthreads();
    // ---- i pass ----
#pragma unroll
    for (int h = 0; h < 8; ++h)
#pragma unroll
        for (int jj = 0; jj < 2; ++jj)
            wb[(h * 8 + jj * 4 + pl) * 17 + eo] = acci[h][jj];
    __syncthreads();
    float bdi = 0.f;
#pragma unroll
    for (int i = 0; i < 16; ++i) bdi += wb[l * 17 + i];

    bdr += crx; bdi += cix;
    float aff = sqrtf(fmaf(ac_r, ac_r, ac_i * ac_i)) + sqrtf(fmaf(bdr, bdr, bdi * bdi));
    float lg = aff * TEMPER;
    uS[4352 + l * 5 + w] = lg;
    __syncthreads();
    {
        float l0 = uS[4352 + l * 5 + 0], l1 = uS[4352 + l * 5 + 1];
        float l2 = uS[4352 + l * 5 + 2], l3 = uS[4352 + l * 5 + 3];
        float m = fmaxf(fmaxf(l0, l1), fmaxf(l2, l3));
        float s = __expf(l0 - m) + __expf(l1 - m) + __expf(l2 - m) + __expf(l3 - m);
        AFF[(unsigned)((nq * 4 + w) * 8 + hh) * 128 + P0 + poff] = __expf(lg - m) / s;
    }
}

// ---------------------------------------------------------------------------
// K6: PV contraction. AFF layout [n][q][b][h][p].  grid 1024, block 256
// ---------------------------------------------------------------------------
__global__ __launch_bounds__(256) void k_pv(
    const float* __restrict__ AFF,
    const float* __restrict__ Vr, const float* __restrict__ Vi,
    float* __restrict__ out)
{
    __shared__ float sA[8 * 132];
    __shared__ float sRed[4 * 1092];
    const int t = threadIdx.x;
    const int nqb = blockIdx.x;
    const int b = nqb & 3, q = (nqb >> 2) & 127, n = nqb >> 9;
#pragma unroll
    for (int j = 0; j < 4; ++j) {
        int idx = t + 256 * j;
        sA[(idx >> 7) * 132 + (idx & 127)] = AFF[(unsigned)nqb * 1024u + idx];
    }
    __syncthreads();
    const int d = t & 63, pp = t >> 6;
    const float* vr = Vr + (n * 512 + b) * 64 + d;
    const float* vi = Vi + (n * 512 + b) * 64 + d;
    float oR[8], oI[8];
#pragma unroll
    for (int h = 0; h < 8; ++h) { oR[h] = 0.f; oI[h] = 0.f; }
    for (int pz = 0; pz < 32; ++pz) {
        int p = pp * 32 + pz;
        float xr = vr[p * 256];
        float xi = vi[p * 256];
#pragma unroll
        for (int h = 0; h < 8; ++h) {
            float a = sA[h * 132 + p];
            oR[h] = fmaf(a, xr, oR[h]);
            oI[h] = fmaf(a, xi, oI[h]);
        }
    }
    float* wb = sRed + pp * 1092;
#pragma unroll
    for (int s = 0; s < 16; ++s) {
        int h = s >> 1;
        wb[d * 17 + s] = (s & 1) ? oI[h] : oR[h];
    }
    __syncthreads();
    const int d2 = t & 63, g = t >> 6;
#pragma unroll
    for (int k = 0; k < 4; ++k) {
        int s = g * 4 + k;
        float v = sRed[0 * 1092 + d2 * 17 + s] + sRed[1 * 1092 + d2 * 17 + s]
                + sRed[2 * 1092 + d2 * 17 + s] + sRed[3 * 1092 + d2 * 17 + s];
        int h = s >> 1, ri = s & 1;
        out[(unsigned)ri * 524288u + ((n * 128 + q) * 4 + b) * 512u + h * 64 + d2] = v;
    }
}

// ---------------------------------------------------------------------------
extern "C" void kernel_launch(void* const* d_in, const int* in_sizes, int n_in,
                              void* d_out, int out_size, void* d_ws, size_t ws_size,
                              hipStream_t stream) {
    (void)in_sizes; (void)n_in; (void)out_size; (void)ws_size;
    const float* q_r  = (const float*)d_in[0];
    const float* q_i  = (const float*)d_in[1];
    const float* k_r  = (const float*)d_in[2];
    const float* k_i  = (const float*)d_in[3];
    const float* v_r  = (const float*)d_in[4];
    const float* v_i  = (const float*)d_in[5];
    const float* e_r  = (const float*)d_in[6];
    const float* e_i  = (const float*)d_in[7];
    const float* WKr_w  = (const float*)d_in[8];
    const float* WKi_w  = (const float*)d_in[10];
    const float* WKRr_w = (const float*)d_in[12];
    const float* WKRr_b = (const float*)d_in[13];
    const float* WKRi_w = (const float*)d_in[14];
    const float* WKRi_b = (const float*)d_in[15];
    const float* WQr_w  = (const float*)d_in[16];
    const float* WQi_w  = (const float*)d_in[18];
    const float* ww_r_g  = (const float*)d_in[20];
    const float* ww_r_bt = (const float*)d_in[21];
    const float* ww_i_g  = (const float*)d_in[22];
    const float* ww_i_bt = (const float*)d_in[23];
    const float* wr_r_g  = (const float*)d_in[24];
    const float* wr_r_bt = (const float*)d_in[25];
    const float* wr_i_g  = (const float*)d_in[26];
    const float* wr_i_bt = (const float*)d_in[27];
    float* ws  = (float*)d_ws;
    float* out = (float*)d_out;

    k_proj<<<dim3(16, 16, 2), 256, 0, stream>>>(q_r, q_i, k_r, k_i,
                                                WQr_w, WQi_w, WKr_w, WKi_w,
                                                ws, ws + PART_);
    k_vvec<<<dim3(32, 16), 256, 0, stream>>>(ws + WQ_R, ws + WQ_I, ws + PART_,
                                             WKRr_w, WKRi_w, WKRr_b, WKRi_b,
                                             wr_r_g, wr_r_bt, wr_i_g, wr_i_bt,
                                             ws + VV_, ws + C_R_, ws + C_I_);
    k_ac<<<dim3(16, 16, 4), 256, 0, stream>>>(ws + WQ_R, ws + WQ_I, ws + WK_R, ws + WK_I,
                                              ws + PART_,
                                              ww_r_g, ww_r_bt, ww_i_g, ww_i_bt,
                                              ws + ACR_, ws + ACI_);
    k_bd<<<dim3(256, 16), 256, 0, stream>>>(e_r, e_i, ws + VV_, ws + C_R_, ws + C_I_,
                                            ws + ACR_, ws + ACI_, ws + AFF_);
    k_pv<<<1024, 256, 0, stream>>>(ws + AFF_, v_r, v_i, out);
}